// Round 3
// baseline (150.660 us; speedup 1.0000x reference)
//
#include <hip/hip_runtime.h>

// LocallyConnected2d: B=16, C=4, H=W=128, K=7, PAD=3, fp32.
// out[b,o,h,w] = mask * sum_{i,t} xpad[b,i,h+dy,w+dx] * wn[o,i,h,w,t]
// cw = weight + 1 at center tap (t=24) for ALL (o,i); wn = |cw|/sum_t|cw|.
//
// R3 structure (fixing latency-bound R2: occ 21%, VALU 16%, HBM 6%):
//  - 4096 blocks (one i-channel each), fp32 atomicAdd into zeroed out.
//    mask distributes over the i-sum, so each block applies it locally.
//  - 2 barriers/block (was 16): float4-coalesced stage into flat LDS panel
//    (LDS layout == global layout; 16B alignment holds because
//    (h*128+w0)*49 % 4 == 0), then 4-threads-per-row in-register L1 sum
//    (shfl_xor quad reduce) + IN-PLACE normalize. No idle-thread phase.
//  - compute reads LDS scalar b32: 4 distinct rows/wave (49-float stride,
//    49%32=17 -> distinct banks), 16-lane broadcast within row: conflict-free.

#define HW 128
#define PW 134            // 128 + 2*3
#define NB 16
#define NC 4
#define KK 49
#define PANEL 784         // 16 pos * 49 taps
#define OSTRIDE 3211264   // 4*16384*49: o-stride in weight floats
#define ISTRIDE 802816    // 16384*49:   i-stride

// ---------------- prep: padded transpose x[b][i][h][w] -> xTp[i][hp][wp][b]
__global__ __launch_bounds__(256) void lc2d_prep(const float* __restrict__ x,
                                                 float* __restrict__ xTp) {
  int idx = blockIdx.x * 256 + threadIdx.x;          // (i, hp, wp)
  if (idx >= NC * PW * PW) return;
  int wp = idx % PW;
  int r  = idx / PW;
  int hp = r % PW;
  int i  = r / PW;
  int h = hp - 3, w = wp - 3;
  bool in = (h >= 0) & (h < HW) & (w >= 0) & (w < HW);
  float v[NB];
#pragma unroll
  for (int b = 0; b < NB; ++b)
    v[b] = in ? x[((b * NC + i) * HW + h) * HW + w] : 0.0f;
  float4* dst = (float4*)(xTp + (size_t)idx * NB);
  dst[0] = make_float4(v[0],  v[1],  v[2],  v[3]);
  dst[1] = make_float4(v[4],  v[5],  v[6],  v[7]);
  dst[2] = make_float4(v[8],  v[9],  v[10], v[11]);
  dst[3] = make_float4(v[12], v[13], v[14], v[15]);
}

// ---------------- main: one (i, h, wc) per block; atomic accumulate over i
template <int MODE>  // 0: x via xTp transpose in ws; 1: direct x (small-ws fallback)
__global__ __launch_bounds__(256) void lc2d_main(const float* __restrict__ weight,
                                                 const float* __restrict__ xsrc,
                                                 float* __restrict__ out) {
  __shared__ __align__(16) float Raw[NC * PANEL];    // 12.25 KB

  const int tid = threadIdx.x;
  const int bid = blockIdx.x;
  const int i   = bid >> 10;          // i outermost: h-contiguous per XCD
  const int r2  = bid & 1023;
  const int h   = r2 >> 3;
  const int wc  = r2 & 7;
  const int w0  = wc * 16;

  // ---- stage 4 o-panels (784 floats each) as coalesced float4s ----
  const size_t wbase = (size_t)i * ISTRIDE + (size_t)(h * HW + w0) * KK;
#pragma unroll
  for (int k = 0; k < 4; ++k) {
    int f = tid + k * 256;
    if (f < 784) {
      int o = f / 196;
      int g = f - o * 196;
      float4 v = *(const float4*)(weight + wbase + (size_t)o * OSTRIDE + 4 * g);
      *(float4*)(&Raw[o * PANEL + 4 * g]) = v;
    }
  }
  __syncthreads();

  // ---- per-(o,ps)-row L1 normalize, in place; 4 threads per row ----
  {
    const int r    = tid >> 2;               // 0..63 row = (o, ps)
    const int q    = tid & 3;                // quarter within row
    const int rowb = (r >> 4) * PANEL + (r & 15) * KK;
    const int t0   = q * 12;                 // taps t0..t0+11 (+ tap48 for q==3)
    float v[13];
#pragma unroll
    for (int j = 0; j < 12; ++j) v[j] = Raw[rowb + t0 + j];
    v[12] = (q == 3) ? Raw[rowb + 48] : 0.f;
    float s = 0.f;
#pragma unroll
    for (int j = 0; j < 13; ++j) s += fabsf(v[j]);
    if (q == 2) s += fabsf(v[0] + 1.f) - fabsf(v[0]);   // center tap t=24 = t0+0
    s += __shfl_xor(s, 1);
    s += __shfl_xor(s, 2);                   // all 4 quad lanes hold full sum
    const float inv = 1.f / s;
    if (q == 2) v[0] += 1.f;
#pragma unroll
    for (int j = 0; j < 12; ++j) Raw[rowb + t0 + j] = fabsf(v[j]) * inv;
    if (q == 3) Raw[rowb + 48] = fabsf(v[12]) * inv;
  }
  __syncthreads();

  // ---- accumulate this i-channel's contribution ----
  const int b   = tid & 15;                  // lane-fastest -> coalesced x loads
  const int pos = tid >> 4;
  const int w   = w0 + pos;
  float acc[NC] = {0.f, 0.f, 0.f, 0.f};

  float xv[7];
#pragma unroll
  for (int dy = 0; dy < 7; ++dy) {
    if (MODE == 0) {
      const float* xr = xsrc + ((size_t)((i * PW + h + dy) * PW + w) * NB + b);
#pragma unroll
      for (int dx = 0; dx < 7; ++dx) xv[dx] = xr[dx * NB];  // 256B/wave, imm offs
    } else {
      int hh = h + dy - 3;
      bool hin = (hh >= 0) & (hh < HW);
#pragma unroll
      for (int dx = 0; dx < 7; ++dx) {
        int ww = w + dx - 3;
        bool in = hin & (ww >= 0) & (ww < HW);
        xv[dx] = in ? xsrc[((b * NC + i) * HW + hh) * HW + ww] : 0.f;
      }
    }
#pragma unroll
    for (int o = 0; o < NC; ++o) {
      const float* wr = &Raw[o * PANEL + pos * KK + dy * 7];
#pragma unroll
      for (int dx = 0; dx < 7; ++dx)
        acc[o] = fmaf(xv[dx], wr[dx], acc[o]);   // broadcast LDS, conflict-free
    }
  }

  // ---- mask (x[b,o,h,w] != 0) + atomic accumulate over i-blocks ----
#pragma unroll
  for (int o = 0; o < NC; ++o) {
    float xc;
    if (MODE == 0)
      xc = xsrc[(size_t)((o * PW + (h + 3)) * PW + (w + 3)) * NB + b];
    else
      xc = xsrc[((b * NC + o) * HW + h) * HW + w];
    atomicAdd(&out[((b * NC + o) * HW + h) * HW + w], (xc != 0.f) ? acc[o] : 0.f);
  }
}

extern "C" void kernel_launch(void* const* d_in, const int* in_sizes, int n_in,
                              void* d_out, int out_size, void* d_ws, size_t ws_size,
                              hipStream_t stream) {
  const float* x      = (const float*)d_in[0];   // (16,4,128,128) fp32
  const float* weight = (const float*)d_in[1];   // (1,4,4,128,128,49) fp32
  float* out = (float*)d_out;                    // (16,4,128,128) fp32

  hipMemsetAsync(d_out, 0, (size_t)out_size * sizeof(float), stream);

  const size_t xtp_bytes = (size_t)NC * PW * PW * NB * sizeof(float); // 4.6 MB
  if (ws_size >= xtp_bytes) {
    float* xTp = (float*)d_ws;
    lc2d_prep<<<(NC * PW * PW + 255) / 256, 256, 0, stream>>>(x, xTp);
    lc2d_main<0><<<4096, 256, 0, stream>>>(weight, xTp, out);
  } else {
    lc2d_main<1><<<4096, 256, 0, stream>>>(weight, x, out);
  }
}

// Round 4
// 118.275 us; speedup vs baseline: 1.2738x; 1.2738x over previous
//
#include <hip/hip_runtime.h>

// LocallyConnected2d: B=16, C=4, H=W=128, K=7, PAD=3, fp32.
// out[b,o,h,w] = mask * sum_{i,t} xpad[b,i,h+dy,w+dx] * wn[o,i,h,w,t]
// cw = weight + 1 at center tap (t=24) for ALL (o,i); wn = |cw|/sum_t|cw|.
//
// R4: phase-free streaming structure.
//  prep1: xTp[i][hp][wp][b]  (padded transpose, 4.6 MB in ws)
//  prep2: wsT[(o*4+i)*49+t][h*128+w] = normalized weights, w innermost
//         (normalize off critical path; main reads weights COALESCED)
//  main : thread=(o, w-of-64), acc[4 b] in regs; x tile in LDS (31 KB),
//         ONE barrier; 196 coalesced indep weight loads + 196 ds_read_b128
//         + 784 FMA per thread. No atomics (full i-sum in block).

#define HW   128
#define PW   134
#define NB   16
#define NC   4
#define KK   49
#define HWHW 16384

#define XTP_FLOATS (NC * PW * PW * NB)        // 1,149,184  (4.6 MB)
#define WT_FLOATS  (NC * NC * KK * HWHW)      // 12,845,056 (51.4 MB)

// ---------------- prep1: padded transpose x[b][i][h][w] -> xTp[i][hp][wp][b]
__global__ __launch_bounds__(256) void lc2d_prep(const float* __restrict__ x,
                                                 float* __restrict__ xTp) {
  int idx = blockIdx.x * 256 + threadIdx.x;          // (i, hp, wp)
  if (idx >= NC * PW * PW) return;
  int wp = idx % PW;
  int r  = idx / PW;
  int hp = r % PW;
  int i  = r / PW;
  int h = hp - 3, w = wp - 3;
  bool in = (h >= 0) & (h < HW) & (w >= 0) & (w < HW);
  float v[NB];
#pragma unroll
  for (int b = 0; b < NB; ++b)
    v[b] = in ? x[((b * NC + i) * HW + h) * HW + w] : 0.0f;
  float4* dst = (float4*)(xTp + (size_t)idx * NB);
  dst[0] = make_float4(v[0],  v[1],  v[2],  v[3]);
  dst[1] = make_float4(v[4],  v[5],  v[6],  v[7]);
  dst[2] = make_float4(v[8],  v[9],  v[10], v[11]);
  dst[3] = make_float4(v[12], v[13], v[14], v[15]);
}

// ---------------- prep2: normalize + transpose weights
// block = (o,i, h, whalf): 64 w x 49 t tile. grid 4096 x 256.
__global__ __launch_bounds__(256) void lc2d_wnorm(const float* __restrict__ weight,
                                                  float* __restrict__ wsT) {
  __shared__ __align__(16) float tile[64 * KK];      // [w][t], 12.25 KB
  const int tid   = threadIdx.x;
  const int bid   = blockIdx.x;
  const int whalf = bid & 1;
  const int h     = (bid >> 1) & 127;
  const int oi    = bid >> 8;                        // o*4+i, 0..15
  const int w0    = whalf * 64;
  const size_t base = ((size_t)oi * HWHW + h * HW + w0) * KK;
  // coalesced float4 stage (base is 64*49-multiple -> 16B aligned)
#pragma unroll
  for (int k = 0; k < 4; ++k) {
    int f = tid + k * 256;
    if (f < 784) *(float4*)&tile[4 * f] = *(const float4*)(weight + base + 4 * f);
  }
  __syncthreads();
  // per-w-row L1 normalize in place; 4 threads per row, quad shfl reduce
  {
    const int r = tid >> 2, q = tid & 3;
    const int t0 = q * 12;                           // q==2 starts at t=24
    float v[13];
#pragma unroll
    for (int j = 0; j < 12; ++j) v[j] = tile[r * KK + t0 + j];
    v[12] = (q == 3) ? tile[r * KK + 48] : 0.f;
    float s = 0.f;
#pragma unroll
    for (int j = 0; j < 13; ++j) s += fabsf(v[j]);
    if (q == 2) s += fabsf(v[0] + 1.f) - fabsf(v[0]);  // center delta, ALL (o,i)
    s += __shfl_xor(s, 1);
    s += __shfl_xor(s, 2);
    const float inv = 1.f / s;
    if (q == 2) v[0] += 1.f;
#pragma unroll
    for (int j = 0; j < 12; ++j) tile[r * KK + t0 + j] = fabsf(v[j]) * inv;
    if (q == 3) tile[r * KK + 48] = fabsf(v[12]) * inv;
  }
  __syncthreads();
  // writeout transposed: wsT[(oi*49+t)*16384 + h*128 + w0 + wl], coalesced;
  // LDS read stride 49 floats -> 2-way bank alias (free).
#pragma unroll
  for (int k = 0; k < 13; ++k) {
    int f = tid + k * 256;
    if (f < 3136) {
      int t = f >> 6, wl = f & 63;
      wsT[((size_t)oi * KK + t) * HWHW + h * HW + w0 + wl] = tile[wl * KK + t];
    }
  }
}

// ---------------- main: fused conv. block=(bq, h, whalf); thread=(o, wt)
__global__ __launch_bounds__(256) void lc2d_fused(const float* __restrict__ wsT,
                                                  const float* __restrict__ xTp,
                                                  float* __restrict__ out) {
  __shared__ __align__(16) float4 tile4[NC * 7 * 70];   // [i][dy][wp].b4, 31.4 KB
  const int tid   = threadIdx.x;
  const int bid   = blockIdx.x;
  const int whalf = bid & 1;
  const int h     = (bid >> 1) & 127;
  const int bq    = bid >> 8;                        // 0..3 (4 b per block)
  const int w0    = whalf * 64;
  const float4* __restrict__ xTp4 = (const float4*)xTp;
  // stage x tile: 1960 float4s, lanes -> consecutive wp
#pragma unroll
  for (int k = 0; k < 8; ++k) {
    int f = tid + k * 256;
    if (f < 1960) {
      int i  = f / 490;
      int r  = f - i * 490;
      int dy = r / 70;
      int wp = r - dy * 70;
      tile4[f] = xTp4[((i * PW + h + dy) * PW + (w0 + wp)) * 4 + bq];
    }
  }
  __syncthreads();

  const int o  = (tid >> 5) & 3;
  const int wt = (tid & 31) | ((tid >> 7) << 5);     // 0..63
  float acc0 = 0.f, acc1 = 0.f, acc2 = 0.f, acc3 = 0.f;

  for (int i = 0; i < NC; ++i) {
    const float* wrow = wsT + ((size_t)(o * NC + i) * KK) * HWHW + h * HW + w0 + wt;
#pragma unroll
    for (int dy = 0; dy < 7; ++dy) {
      const float4* xr = &tile4[(i * 7 + dy) * 70 + wt];
#pragma unroll
      for (int dx = 0; dx < 7; ++dx) {
        float  wv = wrow[(dy * 7 + dx) * HWHW];      // coalesced, 49-deep ILP
        float4 x4 = xr[dx];                          // ds_read_b128, linear
        acc0 = fmaf(wv, x4.x, acc0);
        acc1 = fmaf(wv, x4.y, acc1);
        acc2 = fmaf(wv, x4.z, acc2);
        acc3 = fmaf(wv, x4.w, acc3);
      }
    }
  }
  // mask from x tile (i=o, dy=3, wp=wt+3) and store 4 b's
  float4 m4 = tile4[(o * 7 + 3) * 70 + wt + 3];
  const int wg = w0 + wt;
  out[(((bq * 4 + 0) * NC + o) * HW + h) * HW + wg] = (m4.x != 0.f) ? acc0 : 0.f;
  out[(((bq * 4 + 1) * NC + o) * HW + h) * HW + wg] = (m4.y != 0.f) ? acc1 : 0.f;
  out[(((bq * 4 + 2) * NC + o) * HW + h) * HW + wg] = (m4.z != 0.f) ? acc2 : 0.f;
  out[(((bq * 4 + 3) * NC + o) * HW + h) * HW + wg] = (m4.w != 0.f) ? acc3 : 0.f;
}

// ---------------- fallback (R3 structure) if ws too small ----------------
#define PANEL 784
#define OSTRIDE 3211264
#define ISTRIDE 802816
template <int MODE>
__global__ __launch_bounds__(256) void lc2d_main(const float* __restrict__ weight,
                                                 const float* __restrict__ xsrc,
                                                 float* __restrict__ out) {
  __shared__ __align__(16) float Raw[NC * PANEL];
  const int tid = threadIdx.x;
  const int bid = blockIdx.x;
  const int i   = bid >> 10;
  const int r2  = bid & 1023;
  const int h   = r2 >> 3;
  const int wc  = r2 & 7;
  const int w0  = wc * 16;
  const size_t wbase = (size_t)i * ISTRIDE + (size_t)(h * HW + w0) * KK;
#pragma unroll
  for (int k = 0; k < 4; ++k) {
    int f = tid + k * 256;
    if (f < 784) {
      int o = f / 196;
      int g = f - o * 196;
      *(float4*)(&Raw[o * PANEL + 4 * g]) =
          *(const float4*)(weight + wbase + (size_t)o * OSTRIDE + 4 * g);
    }
  }
  __syncthreads();
  {
    const int r    = tid >> 2;
    const int q    = tid & 3;
    const int rowb = (r >> 4) * PANEL + (r & 15) * KK;
    const int t0   = q * 12;
    float v[13];
#pragma unroll
    for (int j = 0; j < 12; ++j) v[j] = Raw[rowb + t0 + j];
    v[12] = (q == 3) ? Raw[rowb + 48] : 0.f;
    float s = 0.f;
#pragma unroll
    for (int j = 0; j < 13; ++j) s += fabsf(v[j]);
    if (q == 2) s += fabsf(v[0] + 1.f) - fabsf(v[0]);
    s += __shfl_xor(s, 1);
    s += __shfl_xor(s, 2);
    const float inv = 1.f / s;
    if (q == 2) v[0] += 1.f;
#pragma unroll
    for (int j = 0; j < 12; ++j) Raw[rowb + t0 + j] = fabsf(v[j]) * inv;
    if (q == 3) Raw[rowb + 48] = fabsf(v[12]) * inv;
  }
  __syncthreads();
  const int b   = tid & 15;
  const int pos = tid >> 4;
  const int w   = w0 + pos;
  float acc[NC] = {0.f, 0.f, 0.f, 0.f};
  float xv[7];
#pragma unroll
  for (int dy = 0; dy < 7; ++dy) {
    if (MODE == 0) {
      const float* xr = xsrc + ((size_t)((i * PW + h + dy) * PW + w) * NB + b);
#pragma unroll
      for (int dx = 0; dx < 7; ++dx) xv[dx] = xr[dx * NB];
    } else {
      int hh = h + dy - 3;
      bool hin = (hh >= 0) & (hh < HW);
#pragma unroll
      for (int dx = 0; dx < 7; ++dx) {
        int ww = w + dx - 3;
        bool in = hin & (ww >= 0) & (ww < HW);
        xv[dx] = in ? xsrc[((b * NC + i) * HW + hh) * HW + ww] : 0.f;
      }
    }
#pragma unroll
    for (int o = 0; o < NC; ++o) {
      const float* wr = &Raw[o * PANEL + pos * KK + dy * 7];
#pragma unroll
      for (int dx = 0; dx < 7; ++dx)
        acc[o] = fmaf(xv[dx], wr[dx], acc[o]);
    }
  }
#pragma unroll
  for (int o = 0; o < NC; ++o) {
    float xc;
    if (MODE == 0)
      xc = xsrc[(size_t)((o * PW + (h + 3)) * PW + (w + 3)) * NB + b];
    else
      xc = xsrc[((b * NC + o) * HW + h) * HW + w];
    atomicAdd(&out[((b * NC + o) * HW + h) * HW + w], (xc != 0.f) ? acc[o] : 0.f);
  }
}

extern "C" void kernel_launch(void* const* d_in, const int* in_sizes, int n_in,
                              void* d_out, int out_size, void* d_ws, size_t ws_size,
                              hipStream_t stream) {
  const float* x      = (const float*)d_in[0];   // (16,4,128,128) fp32
  const float* weight = (const float*)d_in[1];   // (1,4,4,128,128,49) fp32
  float* out = (float*)d_out;                    // (16,4,128,128) fp32

  const size_t xtp_bytes  = (size_t)XTP_FLOATS * 4;            // 4.6 MB
  const size_t full_bytes = (size_t)(XTP_FLOATS + WT_FLOATS) * 4; // 53.4 MiB

  if (ws_size >= full_bytes) {
    float* xTp = (float*)d_ws;
    float* wsT = (float*)d_ws + XTP_FLOATS;
    lc2d_prep <<<(NC * PW * PW + 255) / 256, 256, 0, stream>>>(x, xTp);
    lc2d_wnorm<<<4096, 256, 0, stream>>>(weight, wsT);
    lc2d_fused<<<1024, 256, 0, stream>>>(wsT, xTp, out);
  } else if (ws_size >= xtp_bytes) {
    hipMemsetAsync(d_out, 0, (size_t)out_size * sizeof(float), stream);
    float* xTp = (float*)d_ws;
    lc2d_prep<<<(NC * PW * PW + 255) / 256, 256, 0, stream>>>(x, xTp);
    lc2d_main<0><<<4096, 256, 0, stream>>>(weight, xTp, out);
  } else {
    hipMemsetAsync(d_out, 0, (size_t)out_size * sizeof(float), stream);
    lc2d_main<1><<<4096, 256, 0, stream>>>(weight, x, out);
  }
}